// Round 8
// baseline (101.033 us; speedup 1.0000x reference)
//
#include <hip/hip_runtime.h>

typedef float f32x2 __attribute__((ext_vector_type(2)));
typedef float f32x4 __attribute__((ext_vector_type(4)));

constexpr int IW = 1024;
constexpr int IH = 1024;
constexpr int BH = 128;

__device__ __forceinline__ float4 splat4(float v){ return make_float4(v,v,v,v); }
__device__ __forceinline__ f32x2 splat2(float v){ f32x2 r; r.x = v; r.y = v; return r; }

__device__ __forceinline__ void nt_store4(const float4& v, float* p) {
    f32x4 t;
    t.x = v.x; t.y = v.y; t.z = v.z; t.w = v.w;
    __builtin_nontemporal_store(t, reinterpret_cast<f32x4*>(p));
}

__global__ __launch_bounds__(256) void demosaick_kernel(
    const float* __restrict__ mosaick,
    const float* __restrict__ gfilt,
    const float* __restrict__ gradfilt,
    float* __restrict__ out)
{
    __shared__ float4 mbuf[258];
    __shared__ float  dlbuf[257];
    __shared__ float  drbuf[257];

    const int tid = threadIdx.x;
    const int y0  = blockIdx.x * BH;
    const int b   = blockIdx.y;
    const int x0  = tid * 4;

    const float* img = mosaick + (size_t)b * IH * IW;

    // weight pairs (gf, df) for packed v_pk_fma_f32 accumulation
    f32x2 wgd[9];
    #pragma unroll
    for (int i = 0; i < 9; ++i) { wgd[i].x = gfilt[i]; wgd[i].y = gradfilt[i]; }

    // m[k] holds row (rd-4+k) when computing d-row rd (center = m[4])
    float4 m[9];
    #pragma unroll
    for (int k = 0; k < 9; ++k) {
        int ry = min(max(y0 - 5 + k, 0), IH - 1);
        m[k] = *reinterpret_cast<const float4*>(img + (size_t)ry * IW + x0);
    }
    float4 mPre = *reinterpret_cast<const float4*>(img + (size_t)min(y0 + 4, IH - 1) * IW + x0);

    if (tid == 0) { dlbuf[0] = 0.f; drbuf[256] = 0.f; }

    auto computeD = [&](const float4 hL, const float4 hR, int rd) -> float4 {
        float h[12];
        h[0]=hL.x; h[1]=hL.y; h[2]=hL.z; h[3]=hL.w;
        h[4]=m[4].x; h[5]=m[4].y; h[6]=m[4].z; h[7]=m[4].w;
        h[8]=hR.x; h[9]=hR.y; h[10]=hR.z; h[11]=hR.w;
        bool vr = ((unsigned)rd) < (unsigned)IH;
        float4 dres;
        #pragma unroll
        for (int j = 0; j < 4; ++j) {
            f32x2 accH = splat2(0.f);   // (ih, dx)
            f32x2 accV = splat2(0.f);   // (iv, dy)
            #pragma unroll
            for (int k = 0; k < 9; ++k)
                accH += wgd[k] * splat2(h[j + k]);
            #pragma unroll
            for (int k = 0; k < 9; ++k)
                accV += wgd[k] * splat2(((const float*)&m[k])[j]);
            float ih = accH.x, dx = accH.y, iv = accV.x, dy = accV.y;
            float adx = fabsf(dx), ady = fabsf(dy);
            float wh = ady * __builtin_amdgcn_rcpf(adx + ady + 1e-5f);
            float gi = fmaf(wh, ih - iv, iv);
            float mc = ((const float*)&m[4])[j];
            int gx = x0 + j;
            bool gsite = (((gx + rd) & 1) == 0);
            ((float*)&dres)[j] = (gsite || !vr) ? 0.f : (mc - gi);
        }
        return dres;
    };

    float4 dA, dB;
    float  dlA, drA, dlB, drB;

    // ---- warmup A: d row y0-1 (center m[4] = row y0-1) ----
    mbuf[tid + 1] = m[4];
    __syncthreads();
    {
        float4 hL = (tid == 0)   ? splat4(m[4].x) : mbuf[tid];
        float4 hR = (tid == 255) ? splat4(m[4].w) : mbuf[tid + 2];
        float4 d0 = computeD(hL, hR, y0 - 1);
        dlbuf[tid + 1] = d0.w; drbuf[tid] = d0.x;
        __syncthreads();
        dA = d0; dlA = dlbuf[tid]; drA = drbuf[tid + 1];
    }
    // ---- warmup B: d row y0 ----
    {
        float4 mNew = mPre;
        mPre = *reinterpret_cast<const float4*>(img + (size_t)min(y0 + 5, IH - 1) * IW + x0);
        mbuf[tid + 1] = m[5];
        __syncthreads();
        float4 hL = (tid == 0)   ? splat4(m[5].x) : mbuf[tid];
        float4 hR = (tid == 255) ? splat4(m[5].w) : mbuf[tid + 2];
        #pragma unroll
        for (int k = 0; k < 8; ++k) m[k] = m[k + 1];
        m[8] = mNew;
        float4 d0 = computeD(hL, hR, y0);
        dlbuf[tid + 1] = d0.w; drbuf[tid] = d0.x;
        __syncthreads();
        dB = d0; dlB = dlbuf[tid]; drB = drbuf[tid + 1];
    }

    const size_t plane = (size_t)IH * IW;
    float* outb = out + (size_t)b * 3 * plane;

    for (int r = y0; r < y0 + BH; ++r) {
        // consume 2-deep prefetch, issue next (row r+6)
        float4 mNew = mPre;
        mPre = *reinterpret_cast<const float4*>(img + (size_t)min(r + 6, IH - 1) * IW + x0);

        // exchange horizontal halo of m row r+1 (= m[5] pre-shift)
        mbuf[tid + 1] = m[5];
        __syncthreads();
        float4 hL = (tid == 0)   ? splat4(m[5].x) : mbuf[tid];
        float4 hR = (tid == 255) ? splat4(m[5].w) : mbuf[tid + 2];

        #pragma unroll
        for (int k = 0; k < 8; ++k) m[k] = m[k + 1];
        m[8] = mNew;

        float4 dC = computeD(hL, hR, r + 1);
        dlbuf[tid + 1] = dC.w; drbuf[tid] = dC.x;
        __syncthreads();
        float dlC = dlbuf[tid], drC = drbuf[tid + 1];

        // ---- chroma + output at row r (m row r = m[3]) ----
        float A6[6] = { dlA, dA.x, dA.y, dA.z, dA.w, drA };
        float B6[6] = { dlB, dB.x, dB.y, dB.z, dB.w, drB };
        float C6[6] = { dlC, dC.x, dC.y, dC.z, dC.w, drC };
        int p = r & 1;
        float4 R4, G4, B4;
        #pragma unroll
        for (int j = 0; j < 4; ++j) {
            float d00  = B6[j + 1];
            float S_ee = d00;
            float S_eo = 0.5f  * (B6[j] + B6[j + 2]);
            float S_oe = 0.5f  * (A6[j + 1] + C6[j + 1]);
            float S_oo = 0.25f * (A6[j] + A6[j + 2] + C6[j] + C6[j + 2]);
            float cr, cb;
            if ((j & 1) == 0) { cr = p ? S_oo : S_eo; cb = p ? S_ee : S_oe; }
            else              { cr = p ? S_oe : S_ee; cb = p ? S_eo : S_oo; }
            float green = ((const float*)&m[3])[j] - d00;
            ((float*)&R4)[j] = green + cr;
            ((float*)&G4)[j] = green;
            ((float*)&B4)[j] = green + cb;
        }
        size_t o = (size_t)r * IW + x0;
        nt_store4(R4, outb + o);
        nt_store4(G4, outb + plane + o);
        nt_store4(B4, outb + 2 * plane + o);

        dA = dB; dlA = dlB; drA = drB;
        dB = dC; dlB = dlC; drB = drC;
    }
}

extern "C" void kernel_launch(void* const* d_in, const int* in_sizes, int n_in,
                              void* d_out, int out_size, void* d_ws, size_t ws_size,
                              hipStream_t stream) {
    const float* mosaick  = (const float*)d_in[0];
    const float* gfilt    = (const float*)d_in[1];
    const float* gradfilt = (const float*)d_in[2];
    float* out = (float*)d_out;

    const int B = in_sizes[0] / (IH * IW);
    dim3 grid(IH / BH, B);
    demosaick_kernel<<<grid, 256, 0, stream>>>(mosaick, gfilt, gradfilt, out);
}

// Round 9
// 88.817 us; speedup vs baseline: 1.1375x; 1.1375x over previous
//
#include <hip/hip_runtime.h>

typedef float f32x2 __attribute__((ext_vector_type(2)));
typedef float f32x4 __attribute__((ext_vector_type(4)));

constexpr int IW = 1024;
constexpr int IH = 1024;
constexpr int BH = 64;

__device__ __forceinline__ float4 splat4(float v){ return make_float4(v,v,v,v); }
__device__ __forceinline__ f32x2 splat2(float v){ f32x2 r; r.x = v; r.y = v; return r; }

__device__ __forceinline__ void nt_store4(const float4& v, float* p) {
    f32x4 t;
    t.x = v.x; t.y = v.y; t.z = v.z; t.w = v.w;
    __builtin_nontemporal_store(t, reinterpret_cast<f32x4*>(p));
}

__global__ __launch_bounds__(256) void demosaick_kernel(
    const float* __restrict__ mosaick,
    const float* __restrict__ gfilt,
    const float* __restrict__ gradfilt,
    float* __restrict__ out)
{
    __shared__ float4 mbuf[258];
    __shared__ float  dlbuf[257];
    __shared__ float  drbuf[257];

    const int tid = threadIdx.x;
    const int y0  = blockIdx.x * BH;
    const int b   = blockIdx.y;
    const int x0  = tid * 4;

    const float* img = mosaick + (size_t)b * IH * IW;

    // weight pairs (gf, df) for packed v_pk_fma_f32 accumulation
    f32x2 wgd[9];
    #pragma unroll
    for (int i = 0; i < 9; ++i) { wgd[i].x = gfilt[i]; wgd[i].y = gradfilt[i]; }

    // m[k] holds row (rd-4+k) when computing d-row rd (center = m[4])
    float4 m[9];
    #pragma unroll
    for (int k = 0; k < 9; ++k) {
        int ry = min(max(y0 - 5 + k, 0), IH - 1);
        m[k] = *reinterpret_cast<const float4*>(img + (size_t)ry * IW + x0);
    }
    float4 mPre = *reinterpret_cast<const float4*>(img + (size_t)min(y0 + 4, IH - 1) * IW + x0);

    if (tid == 0) { dlbuf[0] = 0.f; drbuf[256] = 0.f; }

    auto computeD = [&](const float4 hL, const float4 hR, int rd) -> float4 {
        float h[12];
        h[0]=hL.x; h[1]=hL.y; h[2]=hL.z; h[3]=hL.w;
        h[4]=m[4].x; h[5]=m[4].y; h[6]=m[4].z; h[7]=m[4].w;
        h[8]=hR.x; h[9]=hR.y; h[10]=hR.z; h[11]=hR.w;
        bool vr = ((unsigned)rd) < (unsigned)IH;
        float4 dres;
        #pragma unroll
        for (int j = 0; j < 4; ++j) {
            f32x2 accH = splat2(0.f);   // (ih, dx)
            f32x2 accV = splat2(0.f);   // (iv, dy)
            #pragma unroll
            for (int k = 0; k < 9; ++k)
                accH += wgd[k] * splat2(h[j + k]);
            #pragma unroll
            for (int k = 0; k < 9; ++k)
                accV += wgd[k] * splat2(((const float*)&m[k])[j]);
            float ih = accH.x, dx = accH.y, iv = accV.x, dy = accV.y;
            float adx = fabsf(dx), ady = fabsf(dy);
            float wh = ady * __builtin_amdgcn_rcpf(adx + ady + 1e-5f);
            float gi = fmaf(wh, ih - iv, iv);
            float mc = ((const float*)&m[4])[j];
            int gx = x0 + j;
            bool gsite = (((gx + rd) & 1) == 0);
            ((float*)&dres)[j] = (gsite || !vr) ? 0.f : (mc - gi);
        }
        return dres;
    };

    float4 dA, dB;
    float  dlA, drA, dlB, drB;

    // ---- warmup A: d row y0-1 (center m[4] = row y0-1) ----
    mbuf[tid + 1] = m[4];
    __syncthreads();
    {
        float4 hL = (tid == 0)   ? splat4(m[4].x) : mbuf[tid];
        float4 hR = (tid == 255) ? splat4(m[4].w) : mbuf[tid + 2];
        float4 d0 = computeD(hL, hR, y0 - 1);
        dlbuf[tid + 1] = d0.w; drbuf[tid] = d0.x;
        __syncthreads();
        dA = d0; dlA = dlbuf[tid]; drA = drbuf[tid + 1];
    }
    // ---- warmup B: d row y0 ----
    {
        float4 mNew = mPre;
        mPre = *reinterpret_cast<const float4*>(img + (size_t)min(y0 + 5, IH - 1) * IW + x0);
        mbuf[tid + 1] = m[5];
        __syncthreads();
        float4 hL = (tid == 0)   ? splat4(m[5].x) : mbuf[tid];
        float4 hR = (tid == 255) ? splat4(m[5].w) : mbuf[tid + 2];
        #pragma unroll
        for (int k = 0; k < 8; ++k) m[k] = m[k + 1];
        m[8] = mNew;
        float4 d0 = computeD(hL, hR, y0);
        dlbuf[tid + 1] = d0.w; drbuf[tid] = d0.x;
        __syncthreads();
        dB = d0; dlB = dlbuf[tid]; drB = drbuf[tid + 1];
    }

    const size_t plane = (size_t)IH * IW;
    float* outb = out + (size_t)b * 3 * plane;

    for (int r = y0; r < y0 + BH; ++r) {
        // consume 2-deep prefetch, issue next (row r+6)
        float4 mNew = mPre;
        mPre = *reinterpret_cast<const float4*>(img + (size_t)min(r + 6, IH - 1) * IW + x0);

        // exchange horizontal halo of m row r+1 (= m[5] pre-shift)
        mbuf[tid + 1] = m[5];
        __syncthreads();
        float4 hL = (tid == 0)   ? splat4(m[5].x) : mbuf[tid];
        float4 hR = (tid == 255) ? splat4(m[5].w) : mbuf[tid + 2];

        #pragma unroll
        for (int k = 0; k < 8; ++k) m[k] = m[k + 1];
        m[8] = mNew;

        float4 dC = computeD(hL, hR, r + 1);
        dlbuf[tid + 1] = dC.w; drbuf[tid] = dC.x;
        __syncthreads();
        float dlC = dlbuf[tid], drC = drbuf[tid + 1];

        // ---- chroma + output at row r (m row r = m[3]) ----
        float A6[6] = { dlA, dA.x, dA.y, dA.z, dA.w, drA };
        float B6[6] = { dlB, dB.x, dB.y, dB.z, dB.w, drB };
        float C6[6] = { dlC, dC.x, dC.y, dC.z, dC.w, drC };
        int p = r & 1;
        float4 R4, G4, B4;
        #pragma unroll
        for (int j = 0; j < 4; ++j) {
            float d00  = B6[j + 1];
            float S_ee = d00;
            float S_eo = 0.5f  * (B6[j] + B6[j + 2]);
            float S_oe = 0.5f  * (A6[j + 1] + C6[j + 1]);
            float S_oo = 0.25f * (A6[j] + A6[j + 2] + C6[j] + C6[j + 2]);
            float cr, cb;
            if ((j & 1) == 0) { cr = p ? S_oo : S_eo; cb = p ? S_ee : S_oe; }
            else              { cr = p ? S_oe : S_ee; cb = p ? S_eo : S_oo; }
            float green = ((const float*)&m[3])[j] - d00;
            ((float*)&R4)[j] = green + cr;
            ((float*)&G4)[j] = green;
            ((float*)&B4)[j] = green + cb;
        }
        size_t o = (size_t)r * IW + x0;
        nt_store4(R4, outb + o);
        nt_store4(G4, outb + plane + o);
        nt_store4(B4, outb + 2 * plane + o);

        dA = dB; dlA = dlB; drA = drB;
        dB = dC; dlB = dlC; drB = drC;
    }
}

extern "C" void kernel_launch(void* const* d_in, const int* in_sizes, int n_in,
                              void* d_out, int out_size, void* d_ws, size_t ws_size,
                              hipStream_t stream) {
    const float* mosaick  = (const float*)d_in[0];
    const float* gfilt    = (const float*)d_in[1];
    const float* gradfilt = (const float*)d_in[2];
    float* out = (float*)d_out;

    const int B = in_sizes[0] / (IH * IW);
    dim3 grid(IH / BH, B);
    demosaick_kernel<<<grid, 256, 0, stream>>>(mosaick, gfilt, gradfilt, out);
}